// Round 9
// baseline (624.743 us; speedup 1.0000x reference)
//
#include <hip/hip_runtime.h>
#include <hip/hip_bf16.h>
#include <string.h>

#define BB 4
#define LL 128
#define DM 256
#define VV 50257
#define VPAD 50304   // 786 tiles * 64; also 393 * 128
#define DW 768
#define HH 8
#define EE 32

typedef __attribute__((ext_vector_type(8))) short sh8;    // 8 bf16 = 4 VGPR
typedef __attribute__((ext_vector_type(4))) short sh4;    // 4 bf16 = 2 VGPR
typedef __attribute__((ext_vector_type(4))) float f32x4;  // MFMA accum

static __device__ inline unsigned short bfbits(float x) {
  __hip_bfloat16 h = __float2bfloat16(x);
  unsigned short u;
  __builtin_memcpy(&u, &h, 2);
  return u;
}

// global -> LDS direct 16B copy (per-lane global src, wave-uniform LDS base;
// HW adds lane*16 to the LDS destination)
#define GLDS16(gsrc, ldst)                                                    \
  __builtin_amdgcn_global_load_lds(                                          \
      (const __attribute__((address_space(1))) void*)(gsrc),                 \
      (__attribute__((address_space(3))) void*)(ldst), 16, 0, 0)

#define WAIT_VM(N)                                                           \
  __builtin_amdgcn_sched_barrier(0);                                         \
  asm volatile("s_waitcnt vmcnt(" #N ")" ::: "memory");                      \
  __builtin_amdgcn_sched_barrier(0)
#define WAIT_LGKM0                                                           \
  asm volatile("s_waitcnt lgkmcnt(0)" ::: "memory");                         \
  __builtin_amdgcn_sched_barrier(0)
#define SBARRIER                                                             \
  __builtin_amdgcn_sched_barrier(0);                                         \
  __builtin_amdgcn_s_barrier();                                              \
  __builtin_amdgcn_sched_barrier(0)

// 16x16x16 bf16 MFMA (K=16) for the shuffle-free attention phase 2.
#if __has_builtin(__builtin_amdgcn_mfma_f32_16x16x16bf16_1k)
#define MFMA16(A, B, C) __builtin_amdgcn_mfma_f32_16x16x16bf16_1k(A, B, C, 0, 0, 0)
#elif __has_builtin(__builtin_amdgcn_mfma_f32_16x16x16_bf16)
#define MFMA16(A, B, C) __builtin_amdgcn_mfma_f32_16x16x16_bf16(A, B, C, 0, 0, 0)
#else
static __device__ inline f32x4 mfma16_asm(sh4 a, sh4 b, f32x4 c) {
  asm volatile("v_mfma_f32_16x16x16_bf16 %0, %1, %2, %0"
               : "+v"(c) : "v"(a), "v"(b));
  return c;
}
#define MFMA16(A, B, C) mfma16_asm(A, B, C)
#endif

// ------------- prep: wtrans (blocks 0..95) + qproj (blocks 96..607) ---------
__global__ __launch_bounds__(256) void prep_kernel(
    const float* __restrict__ Wk, const float* __restrict__ Wv,
    unsigned short* __restrict__ Wkt, unsigned short* __restrict__ Wvt,
    const float* __restrict__ tse, const float* __restrict__ Wq,
    const float* __restrict__ bq, unsigned short* __restrict__ Qb) {
  __shared__ float tileS[64][65];
  int bid = blockIdx.x;
  int t = threadIdx.x;
  if (bid < 96) {
    int z = bid / 48, rem = bid - z * 48;
    int x = rem % 12, y = rem / 12;
    const float* src = z ? Wv : Wk;
    unsigned short* dst = z ? Wvt : Wkt;
    int k0 = x * 64, n0 = y * 64;
    int c = t & 63, rb = t >> 6;
#pragma unroll
    for (int j = 0; j < 16; ++j) {
      int r = j * 4 + rb;
      tileS[r][c] = src[(size_t)(k0 + r) * DM + n0 + c];
    }
    __syncthreads();
#pragma unroll
    for (int j = 0; j < 16; ++j) {
      int r = j * 4 + rb;
      dst[(size_t)(n0 + r) * DW + k0 + c] = bfbits(tileS[c][r]);
    }
  } else {
    int r = bid - 96;  // 0..511
    int n = t;         // 0..255
    float* row = &tileS[0][0];
    row[n] = tse[r * DM + n];
    __syncthreads();
    float acc = bq[n];
#pragma unroll 8
    for (int k = 0; k < DM; ++k)
      acc = fmaf(row[k], Wq[k * DM + n], acc);
    const float scale = 0.17677669529663687f * 1.4426950408889634f;  // 1/sqrt(32)*log2e
    Qb[r * DM + n] = bfbits(acc * scale);
  }
}

// ------------- K,V projection via MFMA: [VPAD,768]@[768,256] x2 -------------
// v5: half-row sub-stepped WE staging for 3 blocks/CU.
// WE per half-step: 64 rows ([h*32,h*32+32) u [64+h*32,...)) into ring-2 8KB
// fp32 buffers (WE LDS 32->16KB; total 48KB -> 3 blocks/CU). Every stage is
// issued one half-step before its wait (>= HBM latency); at each wait point
// nothing younger is in flight, so the waits cost nothing extra. K/V dbuf
// as R7 (chunk swizzle, conflicts->0); B-frags read once per kt, reused h=1.
__global__ __launch_bounds__(256, 3) void kvproj_kernel(
    const float* __restrict__ WE, const unsigned short* __restrict__ Wkt,
    const unsigned short* __restrict__ Wvt, const float* __restrict__ bk,
    const float* __restrict__ bv, unsigned short* __restrict__ Kb,
    unsigned short* __restrict__ Vbt) {
  __shared__ float WEh[2][64 * 32];    // 2 x 8192 B (ring-2 by half)
  __shared__ short Kbuf[2][128 * 32];  // 2 x 8192 B
  __shared__ short Vbuf[2][128 * 32];  // 2 x 8192 B

  int bx = blockIdx.x;
  int v0 = (bx >> 1) * 128;
  int colbase = (bx & 1) * 128;
  int t = threadIdx.x;
  int w = t >> 6, lane = t & 63, a = lane & 15, quad = lane >> 4;
  int wm = w >> 1, wn = w & 1;

  // stage WE half (kt,h) into WEh[h]: 512 16B-chunks, 2 per lane.
  // lds row rho<32 -> global row h*32+rho (wm=0 band); rho>=32 -> 64+h*32+rho-32.
  auto stageWEh = [&](int kt, int h) {
#pragma unroll
    for (int i = 0; i < 2; ++i) {
      int s = w * 128 + i * 64 + lane;     // linear LDS 16B-chunk index
      int rho = s >> 3;
      int cc = (s & 7) ^ (rho & 7);        // inverse-swizzled source chunk
      int g = (rho < 32) ? (h * 32 + rho) : (64 + h * 32 + (rho - 32));
      int grow = v0 + g;
      if (grow > VV - 1) grow = VV - 1;    // clamp (pad rows masked at store)
      GLDS16(WE + (size_t)grow * DW + kt * 32 + cc * 4,
             &WEh[h][(w * 128 + i * 64) * 4]);
    }
  };
  // stage K/V tile kt into buffer pb: 4 gload_lds per wave
  auto stageKV = [&](int kt, int pb) {
#pragma unroll
    for (int i = 0; i < 2; ++i) {
      int s = w * 128 + i * 64 + lane;
      int row = s >> 2;
      int cc = (s & 3) ^ ((row >> 1) & 3);
      GLDS16(Wkt + (size_t)(colbase + row) * DW + kt * 32 + cc * 8,
             &Kbuf[pb][(w * 128 + i * 64) * 8]);
      GLDS16(Wvt + (size_t)(colbase + row) * DW + kt * 32 + cc * 8,
             &Vbuf[pb][(w * 128 + i * 64) * 8]);
    }
  };

  f32x4 Ck[4][4], Cv[4][4];
#pragma unroll
  for (int mb = 0; mb < 4; ++mb)
#pragma unroll
    for (int nb = 0; nb < 4; ++nb) {
      Ck[mb][nb] = (f32x4){0.f, 0.f, 0.f, 0.f};
      Cv[mb][nb] = (f32x4){0.f, 0.f, 0.f, 0.f};
    }

  // prologue FIFO: WEh(0,0)[2], KV(0)[4], WEh(0,1)[2], KV(1)[4]
  stageWEh(0, 0);
  stageKV(0, 0);
  stageWEh(0, 1);
  stageKV(1, 1);

  for (int kt = 0; kt < 24; ++kt) {
    int pb = kt & 1;

    // ---- half 0: mb {0,1} ----
    if (kt == 0) {
      WAIT_VM(6);          // drain WEh(0,0)+KV(0); keep WEh(0,1)+KV(1)
    } else {
      WAIT_VM(0);          // outstanding = exactly WEh(kt,0)+KV(kt)
    }
    SBARRIER;
    if (kt > 0) stageWEh(kt, 1);  // W1 consumed at (kt-1,1): safe to restage

    sh8 A0[2], Bk[4], Bv[4];
#pragma unroll
    for (int mu = 0; mu < 2; ++mu) {
      int rho = wm * 32 + mu * 16 + a;
      const float* rp = &WEh[0][rho * 32];
      f32x4 lo = *(const f32x4*)(rp + ((2 * quad) ^ (a & 7)) * 4);
      f32x4 hi = *(const f32x4*)(rp + ((2 * quad + 1) ^ (a & 7)) * 4);
      sh4 l4 = {(short)bfbits(lo[0]), (short)bfbits(lo[1]),
                (short)bfbits(lo[2]), (short)bfbits(lo[3])};
      sh4 h4 = {(short)bfbits(hi[0]), (short)bfbits(hi[1]),
                (short)bfbits(hi[2]), (short)bfbits(hi[3])};
      A0[mu] = __builtin_shufflevector(l4, h4, 0, 1, 2, 3, 4, 5, 6, 7);
    }
#pragma unroll
    for (int nb = 0; nb < 4; ++nb) {
      int krow = (wn * 4 + nb) * 16 + a;
      int cp = (quad ^ ((krow >> 1) & 3)) * 8;
      Bk[nb] = *(const sh8*)&Kbuf[pb][krow * 32 + cp];
      Bv[nb] = *(const sh8*)&Vbuf[pb][krow * 32 + cp];
    }
#pragma unroll
    for (int mu = 0; mu < 2; ++mu)
#pragma unroll
      for (int nb = 0; nb < 4; ++nb) {
        Ck[mu][nb] = __builtin_amdgcn_mfma_f32_16x16x32_bf16(
            A0[mu], Bk[nb], Ck[mu][nb], 0, 0, 0);
        Cv[mu][nb] = __builtin_amdgcn_mfma_f32_16x16x32_bf16(
            A0[mu], Bv[nb], Cv[mu][nb], 0, 0, 0);
      }

    // ---- half 1: mb {2,3} ----
    if (kt == 0) {
      WAIT_VM(4);          // drain WEh(0,1); keep KV(1)
    } else {
      WAIT_VM(0);          // outstanding = exactly WEh(kt,1)
    }
    SBARRIER;
    if (kt < 23) {
      stageWEh(kt + 1, 0);             // W0 consumed at (kt,0): safe
      if (kt > 0) stageKV(kt + 1, pb ^ 1);  // B[pb^1] consumed at kt-1: safe
    }

    sh8 A1[2];
#pragma unroll
    for (int mu = 0; mu < 2; ++mu) {
      int rho = wm * 32 + mu * 16 + a;
      const float* rp = &WEh[1][rho * 32];
      f32x4 lo = *(const f32x4*)(rp + ((2 * quad) ^ (a & 7)) * 4);
      f32x4 hi = *(const f32x4*)(rp + ((2 * quad + 1) ^ (a & 7)) * 4);
      sh4 l4 = {(short)bfbits(lo[0]), (short)bfbits(lo[1]),
                (short)bfbits(lo[2]), (short)bfbits(lo[3])};
      sh4 h4 = {(short)bfbits(hi[0]), (short)bfbits(hi[1]),
                (short)bfbits(hi[2]), (short)bfbits(hi[3])};
      A1[mu] = __builtin_shufflevector(l4, h4, 0, 1, 2, 3, 4, 5, 6, 7);
    }
#pragma unroll
    for (int mu = 0; mu < 2; ++mu)
#pragma unroll
      for (int nb = 0; nb < 4; ++nb) {
        Ck[2 + mu][nb] = __builtin_amdgcn_mfma_f32_16x16x32_bf16(
            A1[mu], Bk[nb], Ck[2 + mu][nb], 0, 0, 0);
        Cv[2 + mu][nb] = __builtin_amdgcn_mfma_f32_16x16x32_bf16(
            A1[mu], Bv[nb], Cv[2 + mu][nb], 0, 0, 0);
      }
  }

  // epilogue: bias + store; K row-major bf16, V TRANSPOSED (Vbt[n][v]).
  float bkv[4], bvv[4];
#pragma unroll
  for (int nb = 0; nb < 4; ++nb) {
    int n = colbase + (wn * 4 + nb) * 16 + a;
    bkv[nb] = bk[n];
    bvv[nb] = bv[n];
  }
#pragma unroll
  for (int mb = 0; mb < 4; ++mb)
#pragma unroll
    for (int nb = 0; nb < 4; ++nb) {
      // half mapping: rows for mb: wm*64 + (mb&1)*16 + (mb>>1)*32? NO --
      // half h=mb>>1 covers global rows wm*64 + h*32 + (mb&1)*16 + a band;
      // C index mb here == 2*h + mu with rows wm*64 + h*32 + mu*16 + ...
      int h = mb >> 1, mu = mb & 1;
      int m0 = v0 + wm * 64 + h * 32 + mu * 16 + quad * 4;
      int n = colbase + (wn * 4 + nb) * 16 + a;
      sh4 vq;
#pragma unroll
      for (int r = 0; r < 4; ++r) {
        int m = m0 + r;
        bool ok = m < VV;
        Kb[(size_t)m * DM + n] = ok ? bfbits(Ck[mb][nb][r] + bkv[nb]) : 0;
        vq[r] = ok ? (short)bfbits(Cv[mb][nb][r] + bvv[nb]) : (short)0;
      }
      *(sh4*)&Vbt[(size_t)n * VPAD + m0] = vq;
    }
}

// ---------------- MFMA attention: barrier-free, LDS-free main loop ----------
// S[tau][r] = P^T[v=quad*4+r][l=tau*16+a] == B-frag of mfma 16x16x16 ->
// phase 2 contracts each wave's 16 v-rows with zero cross-lane movement.
// Epilogue: 2-phase LDS reduction (33KB).
__global__ __launch_bounds__(256) void attn_kernel(
    const unsigned short* __restrict__ Qb, const unsigned short* __restrict__ Kb,
    const unsigned short* __restrict__ Vbt, float* __restrict__ part, int bpb,
    int nc) {
  __shared__ float Cred[2][32][129];  // 33024 B, epilogue only

  int bh = blockIdx.x / bpb;
  int chunk = blockIdx.x - bh * bpb;
  int b = bh >> 3, h = bh & 7;
  int t = threadIdx.x;
  int w = t >> 6;
  int lane = t & 63;
  int a = lane & 15;
  int quad = lane >> 4;

  sh8 qf[8];
  const unsigned short* qbase = Qb + (size_t)(b * LL) * DM + h * EE;
#pragma unroll
  for (int tau = 0; tau < 8; ++tau)
    qf[tau] = *(const sh8*)(qbase + (size_t)(tau * 16 + a) * DM + quad * 8);

  f32x4 C2[2][8];
#pragma unroll
  for (int nb = 0; nb < 2; ++nb)
#pragma unroll
    for (int tau = 0; tau < 8; ++tau)
      C2[nb][tau] = (f32x4){0.f, 0.f, 0.f, 0.f};

  const int ntiles = VPAD >> 6;  // 786

  sh8 af;
  sh4 av[2];
  {
    int v0 = chunk << 6;
    af = *(const sh8*)(Kb + (size_t)(v0 + 16 * w + a) * DM + h * EE + quad * 8);
#pragma unroll
    for (int nb = 0; nb < 2; ++nb)
      av[nb] = *(const sh4*)(Vbt + (size_t)(h * EE + nb * 16 + a) * VPAD +
                             v0 + 16 * w + quad * 4);
  }

  for (int tile = chunk; tile < ntiles; tile += bpb) {
    f32x4 S[8];
#pragma unroll
    for (int tau = 0; tau < 8; ++tau) {
      f32x4 z = {0.f, 0.f, 0.f, 0.f};
      S[tau] = __builtin_amdgcn_mfma_f32_16x16x32_bf16(af, qf[tau], z, 0, 0, 0);
    }

    sh8 af2 = af;
    sh4 av2[2] = {av[0], av[1]};
    int nt = tile + bpb;
    if (nt < ntiles) {
      int v0n = nt << 6;
      af2 = *(const sh8*)(Kb + (size_t)(v0n + 16 * w + a) * DM + h * EE + quad * 8);
#pragma unroll
      for (int nb = 0; nb < 2; ++nb)
        av2[nb] = *(const sh4*)(Vbt + (size_t)(h * EE + nb * 16 + a) * VPAD +
                                v0n + 16 * w + quad * 4);
    }

    float sm[4], inv[4];
#pragma unroll
    for (int r = 0; r < 4; ++r) sm[r] = 0.f;
#pragma unroll
    for (int tau = 0; tau < 8; ++tau)
#pragma unroll
      for (int r = 0; r < 4; ++r) {
        float ex = __builtin_amdgcn_exp2f(S[tau][r]);
        S[tau][r] = ex;
        sm[r] += ex;
      }
#pragma unroll
    for (int msk = 1; msk <= 8; msk <<= 1)
#pragma unroll
      for (int r = 0; r < 4; ++r)
        sm[r] += __shfl_xor(sm[r], msk);
#pragma unroll
    for (int r = 0; r < 4; ++r) inv[r] = 1.f / sm[r];

    sh4 pb[8];
#pragma unroll
    for (int tau = 0; tau < 8; ++tau) {
      pb[tau][0] = (short)bfbits(S[tau][0] * inv[0]);
      pb[tau][1] = (short)bfbits(S[tau][1] * inv[1]);
      pb[tau][2] = (short)bfbits(S[tau][2] * inv[2]);
      pb[tau][3] = (short)bfbits(S[tau][3] * inv[3]);
    }

#pragma unroll
    for (int nb = 0; nb < 2; ++nb)
#pragma unroll
      for (int tau = 0; tau < 8; ++tau)
        C2[nb][tau] = MFMA16(av[nb], pb[tau], C2[nb][tau]);

    af = af2;
    av[0] = av2[0];
    av[1] = av2[1];
  }

  // 2-phase reduction: w0/w1 write planes, w2/w3 add, then sum 2 planes
  if (w < 2) {
#pragma unroll
    for (int nb = 0; nb < 2; ++nb)
#pragma unroll
      for (int tau = 0; tau < 8; ++tau)
#pragma unroll
        for (int r = 0; r < 4; ++r)
          Cred[w][nb * 16 + quad * 4 + r][tau * 16 + a] = C2[nb][tau][r];
  }
  __syncthreads();
  if (w >= 2) {
#pragma unroll
    for (int nb = 0; nb < 2; ++nb)
#pragma unroll
      for (int tau = 0; tau < 8; ++tau)
#pragma unroll
        for (int r = 0; r < 4; ++r)
          Cred[w - 2][nb * 16 + quad * 4 + r][tau * 16 + a] += C2[nb][tau][r];
  }
  __syncthreads();
#pragma unroll
  for (int j = 0; j < 16; ++j) {
    int f = t + 256 * j;          // 0..4095, e-fast
    int e = f & 31, l = f >> 5;
    float s = Cred[0][e][l] + Cred[1][e][l];
    size_t idx = (size_t)(b * LL + l) * DM + h * EE + e;
    if (nc > 1)
      part[(size_t)chunk * (BB * LL * DM) + idx] = s;
    else
      atomicAdd(&part[idx], s);
  }
}

// -------- output projection: (sum_c part[c]) @ Wo + bo -> fp32 out ----------
__global__ __launch_bounds__(256) void outproj_kernel(
    const float* __restrict__ part, const float* __restrict__ Wo,
    const float* __restrict__ bo, float* __restrict__ out, int nc) {
  __shared__ float row[DM];
  int r = blockIdx.x, n = threadIdx.x;
  float s = 0.f;
  for (int c = 0; c < nc; ++c)
    s += part[(size_t)c * (BB * LL * DM) + (size_t)r * DM + n];
  row[n] = s;
  __syncthreads();
  float acc = bo[n];
#pragma unroll 8
  for (int k = 0; k < DM; ++k)
    acc = fmaf(row[k], Wo[k * DM + n], acc);
  out[r * DM + n] = acc;
}

extern "C" void kernel_launch(void* const* d_in, const int* in_sizes, int n_in,
                              void* d_out, int out_size, void* d_ws, size_t ws_size,
                              hipStream_t stream) {
  const float* tse = (const float*)d_in[0];
  const float* WE  = (const float*)d_in[1];
  const float* Wq  = (const float*)d_in[2];
  const float* bq  = (const float*)d_in[3];
  const float* Wk  = (const float*)d_in[4];
  const float* bk  = (const float*)d_in[5];
  const float* Wv  = (const float*)d_in[6];
  const float* bv  = (const float*)d_in[7];
  const float* Wo  = (const float*)d_in[8];
  const float* bo  = (const float*)d_in[9];
  float* out = (float*)d_out;

  // ws: Qb | Kb | Vbt | X.  X holds Wkt+Wvt during prep->kvproj, then is
  // reused for the attn partials (lifetimes disjoint).
  char* ws = (char*)d_ws;
  const size_t QB_BYTES   = (size_t)BB * LL * DM * 2;    // 262144
  const size_t KV_BYTES   = (size_t)VPAD * DM * 2;       // 25755648
  const size_t WT_BYTES   = (size_t)DM * DW * 2;         // 393216
  const size_t PART_BYTES = (size_t)BB * LL * DM * 4;    // 524288
  unsigned short* Qb  = (unsigned short*)ws;
  unsigned short* Kb  = (unsigned short*)(ws + QB_BYTES);
  unsigned short* Vbt = (unsigned short*)(ws + QB_BYTES + KV_BYTES);
  char* X = ws + QB_BYTES + 2 * KV_BYTES;
  unsigned short* Wkt = (unsigned short*)X;
  unsigned short* Wvt = (unsigned short*)(X + WT_BYTES);
  float* part = (float*)X;  // aliases Wkt/Wvt AFTER kvproj is done

  const int BPB = 32;  // v-chunks per (b,h): grid = 32*32 = 1024 blocks

  const size_t NEED_PART =
      QB_BYTES + 2 * KV_BYTES + (size_t)BPB * PART_BYTES;  // ~68.6 MB
  const int nc = (ws_size >= NEED_PART) ? BPB : 1;

  prep_kernel<<<96 + BB * LL, 256, 0, stream>>>(Wk, Wv, Wkt, Wvt, tse, Wq, bq, Qb);
  kvproj_kernel<<<(VPAD / 128) * 2, 256, 0, stream>>>(WE, Wkt, Wvt, bk, bv, Kb, Vbt);
  if (nc == 1)
    (void)hipMemsetAsync(part, 0, PART_BYTES, stream);
  attn_kernel<<<32 * BPB, 256, 0, stream>>>(Qb, Kb, Vbt, part, BPB, nc);
  outproj_kernel<<<BB * LL, 256, 0, stream>>>(part, Wo, bo, out, nc);
}

// Round 10
// 409.361 us; speedup vs baseline: 1.5261x; 1.5261x over previous
//
#include <hip/hip_runtime.h>
#include <hip/hip_bf16.h>
#include <string.h>

#define BB 4
#define LL 128
#define DM 256
#define VV 50257
#define VPAD 50304   // 786 tiles * 64; also 393 * 128
#define DW 768
#define HH 8
#define EE 32

typedef __attribute__((ext_vector_type(8))) short sh8;    // 8 bf16 = 4 VGPR
typedef __attribute__((ext_vector_type(4))) short sh4;    // 4 bf16 = 2 VGPR
typedef __attribute__((ext_vector_type(4))) float f32x4;  // MFMA accum

static __device__ inline unsigned short bfbits(float x) {
  __hip_bfloat16 h = __float2bfloat16(x);
  unsigned short u;
  __builtin_memcpy(&u, &h, 2);
  return u;
}

// global -> LDS direct 16B copy (per-lane global src, wave-uniform LDS base;
// HW adds lane*16 to the LDS destination)
#define GLDS16(gsrc, ldst)                                                    \
  __builtin_amdgcn_global_load_lds(                                          \
      (const __attribute__((address_space(1))) void*)(gsrc),                 \
      (__attribute__((address_space(3))) void*)(ldst), 16, 0, 0)

#define WAIT_VM(N)                                                           \
  __builtin_amdgcn_sched_barrier(0);                                         \
  asm volatile("s_waitcnt vmcnt(" #N ")" ::: "memory");                      \
  __builtin_amdgcn_sched_barrier(0)
#define WAIT_LGKM0                                                           \
  asm volatile("s_waitcnt lgkmcnt(0)" ::: "memory");                         \
  __builtin_amdgcn_sched_barrier(0)
#define SBARRIER                                                             \
  __builtin_amdgcn_sched_barrier(0);                                         \
  __builtin_amdgcn_s_barrier();                                              \
  __builtin_amdgcn_sched_barrier(0)

// 16x16x16 bf16 MFMA (K=16) for the shuffle-free attention phase 2.
#if __has_builtin(__builtin_amdgcn_mfma_f32_16x16x16bf16_1k)
#define MFMA16(A, B, C) __builtin_amdgcn_mfma_f32_16x16x16bf16_1k(A, B, C, 0, 0, 0)
#elif __has_builtin(__builtin_amdgcn_mfma_f32_16x16x16_bf16)
#define MFMA16(A, B, C) __builtin_amdgcn_mfma_f32_16x16x16_bf16(A, B, C, 0, 0, 0)
#else
static __device__ inline f32x4 mfma16_asm(sh4 a, sh4 b, f32x4 c) {
  asm volatile("v_mfma_f32_16x16x16_bf16 %0, %1, %2, %0"
               : "+v"(c) : "v"(a), "v"(b));
  return c;
}
#define MFMA16(A, B, C) mfma16_asm(A, B, C)
#endif

// ------------- prep: wtrans (blocks 0..95) + qproj (blocks 96..607) ---------
__global__ __launch_bounds__(256) void prep_kernel(
    const float* __restrict__ Wk, const float* __restrict__ Wv,
    unsigned short* __restrict__ Wkt, unsigned short* __restrict__ Wvt,
    const float* __restrict__ tse, const float* __restrict__ Wq,
    const float* __restrict__ bq, unsigned short* __restrict__ Qb) {
  __shared__ float tileS[64][65];
  int bid = blockIdx.x;
  int t = threadIdx.x;
  if (bid < 96) {
    int z = bid / 48, rem = bid - z * 48;
    int x = rem % 12, y = rem / 12;
    const float* src = z ? Wv : Wk;
    unsigned short* dst = z ? Wvt : Wkt;
    int k0 = x * 64, n0 = y * 64;
    int c = t & 63, rb = t >> 6;
#pragma unroll
    for (int j = 0; j < 16; ++j) {
      int r = j * 4 + rb;
      tileS[r][c] = src[(size_t)(k0 + r) * DM + n0 + c];
    }
    __syncthreads();
#pragma unroll
    for (int j = 0; j < 16; ++j) {
      int r = j * 4 + rb;
      dst[(size_t)(n0 + r) * DW + k0 + c] = bfbits(tileS[c][r]);
    }
  } else {
    int r = bid - 96;  // 0..511
    int n = t;         // 0..255
    float* row = &tileS[0][0];
    row[n] = tse[r * DM + n];
    __syncthreads();
    float acc = bq[n];
#pragma unroll 8
    for (int k = 0; k < DM; ++k)
      acc = fmaf(row[k], Wq[k * DM + n], acc);
    const float scale = 0.17677669529663687f * 1.4426950408889634f;  // 1/sqrt(32)*log2e
    Qb[r * DM + n] = bfbits(acc * scale);
  }
}

// ------------- K,V projection via MFMA: [VPAD,768]@[768,256] x2 -------------
// R7-measured structure (117us) verbatim: 128x128 tile, WE staged fp32 via
// global_load_lds (2-step cover), depth-2 counted vmcnt, raw barriers, K/V
// chunk swizzle (conflicts->0). ONLY diff vs R7: K stored HEAD-MAJOR
// (Kbh[h][v][32]) so attn's K reads are fully dense 1KB/wave streams
// (was 64B-used-of-512B rows = 2x line-traffic waste).
__global__ __launch_bounds__(256, 2) void kvproj_kernel(
    const float* __restrict__ WE, const unsigned short* __restrict__ Wkt,
    const unsigned short* __restrict__ Wvt, const float* __restrict__ bk,
    const float* __restrict__ bv, unsigned short* __restrict__ Kbh,
    unsigned short* __restrict__ Vbt) {
  __shared__ float WEf[2][128 * 32];   // 2 x 16384 B
  __shared__ short Kbuf[2][128 * 32];  // 2 x  8192 B
  __shared__ short Vbuf[2][128 * 32];  // 2 x  8192 B

  int bx = blockIdx.x;
  int v0 = (bx >> 1) * 128;
  int colbase = (bx & 1) * 128;
  int t = threadIdx.x;
  int w = t >> 6, lane = t & 63, a = lane & 15, quad = lane >> 4;
  int wm = w >> 1, wn = w & 1;

  // stage tile kt into buffer p: 8 global_load_lds per wave (4 WE + 2 K + 2 V)
  auto stage = [&](int kt, int p) {
#pragma unroll
    for (int i = 0; i < 4; ++i) {
      int s = w * 256 + i * 64 + lane;       // linear LDS 16B-chunk index
      int row = s >> 3;
      int cc = (s & 7) ^ (row & 7);          // inverse-swizzled source chunk
      int grow = v0 + row;
      if (grow > VV - 1) grow = VV - 1;      // clamp (pad rows masked at store)
      GLDS16(WE + (size_t)grow * DW + kt * 32 + cc * 4,
             &WEf[p][(w * 256 + i * 64) * 4]);
    }
#pragma unroll
    for (int i = 0; i < 2; ++i) {
      int s = w * 128 + i * 64 + lane;
      int row = s >> 2;
      int cc = (s & 3) ^ ((row >> 1) & 3);   // inverse-swizzled source chunk
      GLDS16(Wkt + (size_t)(colbase + row) * DW + kt * 32 + cc * 8,
             &Kbuf[p][(w * 128 + i * 64) * 8]);
      GLDS16(Wvt + (size_t)(colbase + row) * DW + kt * 32 + cc * 8,
             &Vbuf[p][(w * 128 + i * 64) * 8]);
    }
  };

  f32x4 Ck[4][4], Cv[4][4];
#pragma unroll
  for (int mb = 0; mb < 4; ++mb)
#pragma unroll
    for (int nb = 0; nb < 4; ++nb) {
      Ck[mb][nb] = (f32x4){0.f, 0.f, 0.f, 0.f};
      Cv[mb][nb] = (f32x4){0.f, 0.f, 0.f, 0.f};
    }

  stage(0, 0);
  stage(1, 1);

  for (int kt = 0; kt < 24; ++kt) {
    int p = kt & 1;
    // wait ONLY the oldest stage (kt); stage kt+1 stays in flight
    if (kt < 23) {
      WAIT_VM(8);
    } else {
      WAIT_VM(0);
    }
    SBARRIER;

    // fragment reads from buf[p]
    sh8 A[4], Bk[4], Bv[4];
#pragma unroll
    for (int mb = 0; mb < 4; ++mb) {
      int row = wm * 64 + mb * 16 + a;
      const float* rp = &WEf[p][row * 32];
      f32x4 lo = *(const f32x4*)(rp + ((2 * quad) ^ (a & 7)) * 4);
      f32x4 hi = *(const f32x4*)(rp + ((2 * quad + 1) ^ (a & 7)) * 4);
      sh4 l4 = {(short)bfbits(lo[0]), (short)bfbits(lo[1]),
                (short)bfbits(lo[2]), (short)bfbits(lo[3])};
      sh4 h4 = {(short)bfbits(hi[0]), (short)bfbits(hi[1]),
                (short)bfbits(hi[2]), (short)bfbits(hi[3])};
      A[mb] = __builtin_shufflevector(l4, h4, 0, 1, 2, 3, 4, 5, 6, 7);
    }
#pragma unroll
    for (int nb = 0; nb < 4; ++nb) {
      int krow = (wn * 4 + nb) * 16 + a;
      int cp = (quad ^ ((krow >> 1) & 3)) * 8;
      Bk[nb] = *(const sh8*)&Kbuf[p][krow * 32 + cp];
      Bv[nb] = *(const sh8*)&Vbuf[p][krow * 32 + cp];
    }
#pragma unroll
    for (int mb = 0; mb < 4; ++mb)
#pragma unroll
      for (int nb = 0; nb < 4; ++nb) {
        Ck[mb][nb] = __builtin_amdgcn_mfma_f32_16x16x32_bf16(
            A[mb], Bk[nb], Ck[mb][nb], 0, 0, 0);
        Cv[mb][nb] = __builtin_amdgcn_mfma_f32_16x16x32_bf16(
            A[mb], Bv[nb], Cv[mb][nb], 0, 0, 0);
      }

    // all waves done reading buf[p] before restaging into it
    WAIT_LGKM0;
    SBARRIER;
    if (kt < 22) stage(kt + 2, p);
  }

  // epilogue: bias + store; K HEAD-MAJOR bf16 (Kbh[h][v][e]), V TRANSPOSED
  // (Vbt[n][v]).
  float bkv[4], bvv[4];
#pragma unroll
  for (int nb = 0; nb < 4; ++nb) {
    int n = colbase + (wn * 4 + nb) * 16 + a;
    bkv[nb] = bk[n];
    bvv[nb] = bv[n];
  }
#pragma unroll
  for (int mb = 0; mb < 4; ++mb)
#pragma unroll
    for (int nb = 0; nb < 4; ++nb) {
      int m0 = v0 + wm * 64 + mb * 16 + quad * 4;
      int n = colbase + (wn * 4 + nb) * 16 + a;
      int hh = n >> 5, e = n & 31;
      sh4 vq;
#pragma unroll
      for (int r = 0; r < 4; ++r) {
        int m = m0 + r;
        bool ok = m < VV;
        Kbh[((size_t)hh * VPAD + m) * EE + e] =
            ok ? bfbits(Ck[mb][nb][r] + bkv[nb]) : 0;
        vq[r] = ok ? (short)bfbits(Cv[mb][nb][r] + bvv[nb]) : (short)0;
      }
      *(sh4*)&Vbt[(size_t)n * VPAD + m0] = vq;  // 8B store, pad cols zeroed
    }
}

// ---------------- MFMA attention: barrier-free, LDS-free main loop ----------
// S[tau][r] = P^T[v=quad*4+r][l=tau*16+a] == B-frag of mfma 16x16x16 ->
// phase 2 contracts each wave's 16 v-rows with zero cross-lane movement.
// K reads now fully dense (head-major Kbh): 1KB contiguous per wave per tile.
// Epilogue: 2-phase LDS reduction (33KB).
__global__ __launch_bounds__(256) void attn_kernel(
    const unsigned short* __restrict__ Qb, const unsigned short* __restrict__ Kbh,
    const unsigned short* __restrict__ Vbt, float* __restrict__ part, int bpb,
    int nc) {
  __shared__ float Cred[2][32][129];  // 33024 B, epilogue only

  int bh = blockIdx.x / bpb;
  int chunk = blockIdx.x - bh * bpb;
  int b = bh >> 3, h = bh & 7;
  int t = threadIdx.x;
  int w = t >> 6;
  int lane = t & 63;
  int a = lane & 15;
  int quad = lane >> 4;

  const unsigned short* Kh = Kbh + (size_t)h * VPAD * EE;

  sh8 qf[8];
  const unsigned short* qbase = Qb + (size_t)(b * LL) * DM + h * EE;
#pragma unroll
  for (int tau = 0; tau < 8; ++tau)
    qf[tau] = *(const sh8*)(qbase + (size_t)(tau * 16 + a) * DM + quad * 8);

  f32x4 C2[2][8];
#pragma unroll
  for (int nb = 0; nb < 2; ++nb)
#pragma unroll
    for (int tau = 0; tau < 8; ++tau)
      C2[nb][tau] = (f32x4){0.f, 0.f, 0.f, 0.f};

  const int ntiles = VPAD >> 6;  // 786

  sh8 af;
  sh4 av[2];
  {
    int v0 = chunk << 6;
    af = *(const sh8*)(Kh + (size_t)(v0 + 16 * w + a) * EE + quad * 8);
#pragma unroll
    for (int nb = 0; nb < 2; ++nb)
      av[nb] = *(const sh4*)(Vbt + (size_t)(h * EE + nb * 16 + a) * VPAD +
                             v0 + 16 * w + quad * 4);
  }

  for (int tile = chunk; tile < ntiles; tile += bpb) {
    f32x4 S[8];
#pragma unroll
    for (int tau = 0; tau < 8; ++tau) {
      f32x4 z = {0.f, 0.f, 0.f, 0.f};
      S[tau] = __builtin_amdgcn_mfma_f32_16x16x32_bf16(af, qf[tau], z, 0, 0, 0);
    }

    sh8 af2 = af;
    sh4 av2[2] = {av[0], av[1]};
    int nt = tile + bpb;
    if (nt < ntiles) {
      int v0n = nt << 6;
      af2 = *(const sh8*)(Kh + (size_t)(v0n + 16 * w + a) * EE + quad * 8);
#pragma unroll
      for (int nb = 0; nb < 2; ++nb)
        av2[nb] = *(const sh4*)(Vbt + (size_t)(h * EE + nb * 16 + a) * VPAD +
                                v0n + 16 * w + quad * 4);
    }

    float sm[4], inv[4];
#pragma unroll
    for (int r = 0; r < 4; ++r) sm[r] = 0.f;
#pragma unroll
    for (int tau = 0; tau < 8; ++tau)
#pragma unroll
      for (int r = 0; r < 4; ++r) {
        float ex = __builtin_amdgcn_exp2f(S[tau][r]);
        S[tau][r] = ex;
        sm[r] += ex;
      }
#pragma unroll
    for (int msk = 1; msk <= 8; msk <<= 1)
#pragma unroll
      for (int r = 0; r < 4; ++r)
        sm[r] += __shfl_xor(sm[r], msk);
#pragma unroll
    for (int r = 0; r < 4; ++r) inv[r] = 1.f / sm[r];

    sh4 pb[8];
#pragma unroll
    for (int tau = 0; tau < 8; ++tau) {
      pb[tau][0] = (short)bfbits(S[tau][0] * inv[0]);
      pb[tau][1] = (short)bfbits(S[tau][1] * inv[1]);
      pb[tau][2] = (short)bfbits(S[tau][2] * inv[2]);
      pb[tau][3] = (short)bfbits(S[tau][3] * inv[3]);
    }

#pragma unroll
    for (int nb = 0; nb < 2; ++nb)
#pragma unroll
      for (int tau = 0; tau < 8; ++tau)
        C2[nb][tau] = MFMA16(av[nb], pb[tau], C2[nb][tau]);

    af = af2;
    av[0] = av2[0];
    av[1] = av2[1];
  }

  // 2-phase reduction: w0/w1 write planes, w2/w3 add, then sum 2 planes
  if (w < 2) {
#pragma unroll
    for (int nb = 0; nb < 2; ++nb)
#pragma unroll
      for (int tau = 0; tau < 8; ++tau)
#pragma unroll
        for (int r = 0; r < 4; ++r)
          Cred[w][nb * 16 + quad * 4 + r][tau * 16 + a] = C2[nb][tau][r];
  }
  __syncthreads();
  if (w >= 2) {
#pragma unroll
    for (int nb = 0; nb < 2; ++nb)
#pragma unroll
      for (int tau = 0; tau < 8; ++tau)
#pragma unroll
        for (int r = 0; r < 4; ++r)
          Cred[w - 2][nb * 16 + quad * 4 + r][tau * 16 + a] += C2[nb][tau][r];
  }
  __syncthreads();
#pragma unroll
  for (int j = 0; j < 16; ++j) {
    int f = t + 256 * j;          // 0..4095, e-fast
    int e = f & 31, l = f >> 5;
    float s = Cred[0][e][l] + Cred[1][e][l];
    size_t idx = (size_t)(b * LL + l) * DM + h * EE + e;
    if (nc > 1)
      part[(size_t)chunk * (BB * LL * DM) + idx] = s;
    else
      atomicAdd(&part[idx], s);
  }
}

// -------- output projection: (sum_c part[c]) @ Wo + bo -> fp32 out ----------
__global__ __launch_bounds__(256) void outproj_kernel(
    const float* __restrict__ part, const float* __restrict__ Wo,
    const float* __restrict__ bo, float* __restrict__ out, int nc) {
  __shared__ float row[DM];
  int r = blockIdx.x, n = threadIdx.x;
  float s = 0.f;
  for (int c = 0; c < nc; ++c)
    s += part[(size_t)c * (BB * LL * DM) + (size_t)r * DM + n];
  row[n] = s;
  __syncthreads();
  float acc = bo[n];
#pragma unroll 8
  for (int k = 0; k < DM; ++k)
    acc = fmaf(row[k], Wo[k * DM + n], acc);
  out[r * DM + n] = acc;
}

extern "C" void kernel_launch(void* const* d_in, const int* in_sizes, int n_in,
                              void* d_out, int out_size, void* d_ws, size_t ws_size,
                              hipStream_t stream) {
  const float* tse = (const float*)d_in[0];
  const float* WE  = (const float*)d_in[1];
  const float* Wq  = (const float*)d_in[2];
  const float* bq  = (const float*)d_in[3];
  const float* Wk  = (const float*)d_in[4];
  const float* bk  = (const float*)d_in[5];
  const float* Wv  = (const float*)d_in[6];
  const float* bv  = (const float*)d_in[7];
  const float* Wo  = (const float*)d_in[8];
  const float* bo  = (const float*)d_in[9];
  float* out = (float*)d_out;

  // ws: Qb | Kbh | Vbt | X.  X holds Wkt+Wvt during prep->kvproj, then is
  // reused for the attn partials (lifetimes disjoint).
  char* ws = (char*)d_ws;
  const size_t QB_BYTES   = (size_t)BB * LL * DM * 2;    // 262144
  const size_t KV_BYTES   = (size_t)VPAD * DM * 2;       // 25755648
  const size_t WT_BYTES   = (size_t)DM * DW * 2;         // 393216
  const size_t PART_BYTES = (size_t)BB * LL * DM * 4;    // 524288
  unsigned short* Qb  = (unsigned short*)ws;
  unsigned short* Kbh = (unsigned short*)(ws + QB_BYTES);
  unsigned short* Vbt = (unsigned short*)(ws + QB_BYTES + KV_BYTES);
  char* X = ws + QB_BYTES + 2 * KV_BYTES;
  unsigned short* Wkt = (unsigned short*)X;
  unsigned short* Wvt = (unsigned short*)(X + WT_BYTES);
  float* part = (float*)X;  // aliases Wkt/Wvt AFTER kvproj is done

  const int BPB = 32;  // v-chunks per (b,h): grid = 32*32 = 1024 blocks

  const size_t NEED_PART =
      QB_BYTES + 2 * KV_BYTES + (size_t)BPB * PART_BYTES;  // ~68.6 MB
  const int nc = (ws_size >= NEED_PART) ? BPB : 1;

  prep_kernel<<<96 + BB * LL, 256, 0, stream>>>(Wk, Wv, Wkt, Wvt, tse, Wq, bq, Qb);
  kvproj_kernel<<<(VPAD / 128) * 2, 256, 0, stream>>>(WE, Wkt, Wvt, bk, bv, Kbh, Vbt);
  if (nc == 1)
    (void)hipMemsetAsync(part, 0, PART_BYTES, stream);
  attn_kernel<<<32 * BPB, 256, 0, stream>>>(Qb, Kbh, Vbt, part, BPB, nc);
  outproj_kernel<<<BB * LL, 256, 0, stream>>>(part, Wo, bo, out, nc);
}